// Round 19
// baseline (289.491 us; speedup 1.0000x reference)
//
#include <hip/hip_runtime.h>
#include <math.h>

#define BB 4
#define TT 4096
#define DD 2048
#define HH 16
#define HDIM 128
#define KSEL 512
#define NBH (BB*HH)

using short8  = __attribute__((ext_vector_type(8))) short;
using short4v = __attribute__((ext_vector_type(4))) short;
using f32x4   = __attribute__((ext_vector_type(4))) float;

__device__ __forceinline__ short f2bf(float f) {
  unsigned u = __float_as_uint(f);
  u += 0x7fffu + ((u >> 16) & 1u);   // round-nearest-even
  return (short)(u >> 16);
}
__device__ __forceinline__ float bf2f(short s) {
  return __uint_as_float(((unsigned)(unsigned short)s) << 16);
}

// async global->LDS, 16B per lane; LDS dest wave-uniform base + lane*16
__device__ __forceinline__ void gload16(const short* g, short* l) {
  __builtin_amdgcn_global_load_lds(
      (const __attribute__((address_space(1))) void*)g,
      (__attribute__((address_space(3))) void*)l, 16, 0, 0);
}

// ---------------- K1: router scores, split-K f32 GEMM; fused bf16-x side-write ----------------
__global__ __launch_bounds__(256) void k_router2(const float* __restrict__ x,
    const float* __restrict__ wr, float* __restrict__ part,
    short* __restrict__ xb, const int writeXb) {
  __shared__ __align__(16) float Xs[128][36];
  __shared__ __align__(16) float Ws[16][36];
  const int tb = blockIdx.x, kq = blockIdx.y;
  const int tid = threadIdx.x;
  const int row0 = tb * 128;
  const int sr8 = tid >> 3, sc8 = (tid & 7) * 4;   // stage map: 8 thr/row, 128B runs
  const int tq = tid >> 2, hq = tid & 3;           // compute map
  const int kbase = kq * 256;
  float acc[2][4];
#pragma unroll
  for (int i = 0; i < 2; ++i)
#pragma unroll
    for (int j = 0; j < 4; ++j) acc[i][j] = 0.f;
  float4 xr[4], wreg;
  {
#pragma unroll
    for (int p = 0; p < 4; ++p)
      xr[p] = *(const float4*)(x + (size_t)(row0 + sr8 + p * 32) * DD + kbase + sc8);
    if (tid < 128) wreg = *(const float4*)(wr + (size_t)(tid >> 3) * DD + kbase + (tid & 7) * 4);
  }
  for (int c = 0; c < 8; ++c) {
    if (c) __syncthreads();
#pragma unroll
    for (int p = 0; p < 4; ++p) {
      *(float4*)&Xs[sr8 + p * 32][sc8] = xr[p];
      if (writeXb) {
        short4v b4;
        b4[0] = f2bf(xr[p].x); b4[1] = f2bf(xr[p].y);
        b4[2] = f2bf(xr[p].z); b4[3] = f2bf(xr[p].w);
        *(short4v*)(xb + (size_t)(row0 + sr8 + p * 32) * DD + kbase + c * 32 + sc8) = b4;
      }
    }
    if (tid < 128) *(float4*)&Ws[tid >> 3][(tid & 7) * 4] = wreg;
    __syncthreads();
    if (c < 7) {
      const int k0 = kbase + (c + 1) * 32;
#pragma unroll
      for (int p = 0; p < 4; ++p)
        xr[p] = *(const float4*)(x + (size_t)(row0 + sr8 + p * 32) * DD + k0 + sc8);
      if (tid < 128) wreg = *(const float4*)(wr + (size_t)(tid >> 3) * DD + k0 + (tid & 7) * 4);
    }
#pragma unroll
    for (int k4 = 0; k4 < 8; ++k4) {
      float4 xv0 = *(const float4*)&Xs[tq][k4 * 4];
      float4 xv1 = *(const float4*)&Xs[tq + 64][k4 * 4];
#pragma unroll
      for (int j = 0; j < 4; ++j) {
        float4 wv4 = *(const float4*)&Ws[hq + j * 4][k4 * 4];
        acc[0][j] += xv0.x * wv4.x + xv0.y * wv4.y + xv0.z * wv4.z + xv0.w * wv4.w;
        acc[1][j] += xv1.x * wv4.x + xv1.y * wv4.y + xv1.z * wv4.z + xv1.w * wv4.w;
      }
    }
  }
#pragma unroll
  for (int i = 0; i < 2; ++i) {
    int tg = row0 + tq + i * 64;
    int b = tg >> 12, t = tg & (TT - 1);
#pragma unroll
    for (int j = 0; j < 4; ++j)
      part[((size_t)kq * NBH + (b * HH + hq + j * 4)) * TT + t] = acc[i][j];
  }
}

// ---------------- K2: fused {per-(b,h) top-512 radix-select + inverse map} | {f32->bf16 weight cvt} ----------------
// Blocks [0,NBH): top-k (critical path, dispatched first). Blocks [NBH, NBH+4096): weight cvt
// (fills the idle CUs during the latency-bound top-k). Outputs independent; deterministic.
__global__ __launch_bounds__(512) void k_topk(const float* __restrict__ part,
                                              int* __restrict__ idx,
                                              int* __restrict__ inv,
                                              const float* __restrict__ wq,
                                              const float* __restrict__ wk,
                                              const float* __restrict__ wv,
                                              const float* __restrict__ wo,
                                              short* __restrict__ wdst) {
  __shared__ unsigned hist[256];
  __shared__ unsigned ssum[257];
  __shared__ unsigned wtot[8];
  __shared__ unsigned sh_b;
  const int bx = blockIdx.x, tid = threadIdx.x;
  if (bx >= NBH) {
    // weight conversion: 512 thr x 8 elems = 4096 elems/block; 1024 blocks/weight
    const int cb = bx - NBH;
    const int wsel = cb >> 10;
    const float* s = (wsel == 0) ? wq : (wsel == 1) ? wk : (wsel == 2) ? wv : wo;
    size_t base = (size_t)(cb & 1023) * 4096 + (size_t)tid * 8;
    float4 a = *(const float4*)(s + base);
    float4 b = *(const float4*)(s + base + 4);
    short8 o;
    o[0] = f2bf(a.x); o[1] = f2bf(a.y); o[2] = f2bf(a.z); o[3] = f2bf(a.w);
    o[4] = f2bf(b.x); o[5] = f2bf(b.y); o[6] = f2bf(b.z); o[7] = f2bf(b.w);
    *(short8*)&wdst[(size_t)wsel * 4194304 + base] = o;
    return;
  }
  const int bh = bx;
  const int lane = tid & 63, wvx = tid >> 6;
  const size_t S = (size_t)NBH * TT;
  const float* pb = part + (size_t)bh * TT + tid * 8;
  unsigned key[8];
  {
    float4 s0 = *(const float4*)(pb);
    float4 s1 = *(const float4*)(pb + 4);
#pragma unroll
    for (int k = 1; k < 8; ++k) {
      float4 v0 = *(const float4*)(pb + k * S);
      float4 v1 = *(const float4*)(pb + k * S + 4);
      s0.x += v0.x; s0.y += v0.y; s0.z += v0.z; s0.w += v0.w;
      s1.x += v1.x; s1.y += v1.y; s1.z += v1.z; s1.w += v1.w;
    }
    float vs[8] = {s0.x, s0.y, s0.z, s0.w, s1.x, s1.y, s1.z, s1.w};
#pragma unroll
    for (int i = 0; i < 8; ++i) {
      unsigned u = __float_as_uint(vs[i]);
      key[i] = (u & 0x80000000u) ? ~u : (u | 0x80000000u);  // monotone map
    }
  }
  unsigned prefix = 0, need = KSEL;
  for (int shift = 24; shift >= 0; shift -= 8) {
    if (tid < 256) hist[tid] = 0;
    __syncthreads();
#pragma unroll
    for (int i = 0; i < 8; ++i) {
      bool m = (shift == 24) || ((key[i] >> (shift + 8)) == prefix);
      if (m) atomicAdd(&hist[(key[i] >> shift) & 255], 1u);
    }
    __syncthreads();
    if (wvx == 0) {
      unsigned v0 = hist[lane * 4], v1 = hist[lane * 4 + 1];
      unsigned v2 = hist[lane * 4 + 2], v3 = hist[lane * 4 + 3];
      unsigned s3 = v3, s2 = v2 + s3, s1 = v1 + s2, s0 = v0 + s1;
      unsigned t = s0;
#pragma unroll
      for (int off = 1; off < 64; off <<= 1) {
        unsigned o = __shfl_down(t, off);
        if (lane + off < 64) t += o;
      }
      unsigned above = t - s0;
      ssum[lane * 4]     = s0 + above;
      ssum[lane * 4 + 1] = s1 + above;
      ssum[lane * 4 + 2] = s2 + above;
      ssum[lane * 4 + 3] = s3 + above;
      if (lane == 0) ssum[256] = 0;
    }
    __syncthreads();
    if (tid < 256) {
      if (ssum[tid] >= need && ssum[tid + 1] < need) sh_b = (unsigned)tid;
    }
    __syncthreads();
    unsigned bstar = sh_b;
    need -= ssum[bstar + 1];
    prefix = (shift == 24) ? bstar : ((prefix << 8) | bstar);
  }
  const unsigned thr = prefix;
  unsigned cgt = 0, ceq = 0;
#pragma unroll
  for (int i = 0; i < 8; ++i) { cgt += (key[i] > thr); ceq += (key[i] == thr); }
  unsigned packed = (cgt << 16) | ceq;
  unsigned inc = packed;
#pragma unroll
  for (int off = 1; off < 64; off <<= 1) {
    unsigned o = __shfl_up(inc, off);
    if (lane >= off) inc += o;
  }
  if (lane == 63) wtot[wvx] = inc;
  __syncthreads();
  unsigned wbase = 0;
#pragma unroll
  for (int w2 = 0; w2 < 8; ++w2) wbase += (w2 < wvx) ? wtot[w2] : 0u;
  unsigned base = wbase + inc - packed;
  unsigned gt_before = base >> 16, eq_before = base & 0xffffu;
  int* op = idx + bh * KSEL;
  int* invrow = inv + (size_t)bh * TT;
#pragma unroll
  for (int i = 0; i < 8; ++i) {
    bool isgt = key[i] > thr, iseq = key[i] == thr;
    bool sel = isgt || (iseq && eq_before < need);
    int pos = -1;
    if (sel) {
      pos = (int)(gt_before + (eq_before < need ? eq_before : need));
      op[pos] = tid * 8 + i;
    }
    invrow[tid * 8 + i] = pos;
    gt_before += isgt; eq_before += iseq;
  }
}

// ---------------- K3: merged gathered QKV projection via bf16 MFMA (round-10/15 proven) ----------------
template <int AB>
__global__ __launch_bounds__(256, 2) void k_qkv_mfma(
    const float* __restrict__ x, const short* __restrict__ xb,
    const short* __restrict__ wqb, const short* __restrict__ wkb,
    const short* __restrict__ wvb, const int* __restrict__ idx,
    short* __restrict__ q_s, short* __restrict__ k_s, short* __restrict__ v_t) {
  __shared__ __align__(16) short As[64 * 64];
  __shared__ __align__(16) short Bs[3][128 * 64];
  __shared__ int tIdx[64];
  const int L = blockIdx.x;            // [bhhi:3][rt:3][xcd:3]
  const int xcd = L & 7;
  const int bh = xcd * 8 + (L >> 6);
  const int rt = (L >> 3) & 7;
  const int b = bh >> 4, h = bh & 15;
  const int tid = threadIdx.x;
  if (tid < 64) tIdx[tid] = idx[bh * KSEL + rt * 64 + tid];
  __syncthreads();
  const int lane = tid & 63, w = tid >> 6;
  const int g = lane >> 4, r15 = lane & 15;
  const int lcol8 = lane >> 3, lslot = lane & 7; // stage lane mapping
  const float* aPtr = nullptr;
  const short* aSrc0 = nullptr; const short* aSrc1 = nullptr;
  int arow = 0, rm = 0;
  if constexpr (AB) {
    int rowA0 = w * 16 + lcol8;
    int rowA1 = rowA0 + 8;
    aSrc0 = xb + ((size_t)b * TT + tIdx[rowA0]) * DD + ((lslot ^ lcol8) << 3);
    aSrc1 = xb + ((size_t)b * TT + tIdx[rowA1]) * DD + ((lslot ^ lcol8) << 3);
  } else {
    arow = tid >> 2;
    rm = arow & 7;
    aPtr = x + ((size_t)b * TT + tIdx[arow]) * DD + (tid & 3) * 16;
  }
  f32x4 acc[4][6];
#pragma unroll
  for (int m = 0; m < 4; ++m)
#pragma unroll
    for (int n = 0; n < 6; ++n) acc[m][n] = (f32x4){0.f, 0.f, 0.f, 0.f};
  for (int k0 = 0; k0 < DD; k0 += 64) {
    __syncthreads();
    {
      if constexpr (AB) {
        gload16(aSrc0 + k0, &As[(w * 16) * 64]);
        gload16(aSrc1 + k0, &As[(w * 16 + 8) * 64]);
      } else {
        float4 a0 = *(const float4*)(aPtr + k0);
        float4 a1 = *(const float4*)(aPtr + k0 + 4);
        float4 a2 = *(const float4*)(aPtr + k0 + 8);
        float4 a3 = *(const float4*)(aPtr + k0 + 12);
        short8 p0, p1;
        p0[0] = f2bf(a0.x); p0[1] = f2bf(a0.y); p0[2] = f2bf(a0.z); p0[3] = f2bf(a0.w);
        p0[4] = f2bf(a1.x); p0[5] = f2bf(a1.y); p0[6] = f2bf(a1.z); p0[7] = f2bf(a1.w);
        p1[0] = f2bf(a2.x); p1[1] = f2bf(a2.y); p1[2] = f2bf(a2.z); p1[3] = f2bf(a2.w);
        p1[4] = f2bf(a3.x); p1[5] = f2bf(a3.y); p1[6] = f2bf(a3.z); p1[7] = f2bf(a3.w);
        int kq = tid & 3;
        *(short8*)&As[arow * 64 + ((2 * kq) ^ rm) * 8] = p0;
        *(short8*)&As[arow * 64 + ((2 * kq + 1) ^ rm) * 8] = p1;
      }
#pragma unroll
      for (int t = 0; t < 12; ++t) {
        int gi = w * 12 + t;
        int p = gi >> 4;
        int c0 = (gi & 15) << 3;
        int col = c0 + lcol8;
        const short* wsrc = (p == 0 ? wqb : p == 1 ? wkb : wvb)
                          + ((size_t)(h * HDIM + col)) * DD + k0 + ((lslot ^ (col & 7)) << 3);
        gload16(wsrc, &Bs[p][c0 * 64]);
      }
    }
    __syncthreads();
#pragma unroll
    for (int ks = 0; ks < 2; ++ks) {
      short8 af[4], bfr[6];
#pragma unroll
      for (int m = 0; m < 4; ++m) {
        int row = m * 16 + r15;
        af[m] = *(const short8*)&As[row * 64 + ((ks * 4 + g) ^ (row & 7)) * 8];
      }
#pragma unroll
      for (int n = 0; n < 6; ++n) {
        int nf = w * 6 + n;
        int colr = (nf & 7) * 16 + r15;
        bfr[n] = *(const short8*)&Bs[nf >> 3][colr * 64 + ((ks * 4 + g) ^ (colr & 7)) * 8];
      }
#pragma unroll
      for (int m = 0; m < 4; ++m)
#pragma unroll
        for (int n = 0; n < 6; ++n)
          acc[m][n] = __builtin_amdgcn_mfma_f32_16x16x32_bf16(af[m], bfr[n], acc[m][n], 0, 0, 0);
    }
  }
#pragma unroll
  for (int n = 0; n < 6; ++n) {
    int nf = w * 6 + n;
    int p = nf >> 3;
    int col = (nf & 7) * 16 + r15;
    if (p == 2) {
#pragma unroll
      for (int m = 0; m < 4; ++m) {
        short4v pk;
#pragma unroll
        for (int r = 0; r < 4; ++r) pk[r] = f2bf(acc[m][n][r]);
        *(short4v*)&v_t[((size_t)bh * HDIM + col) * KSEL + rt * 64 + m * 16 + g * 4] = pk;
      }
    } else {
      short* dp = (p == 0) ? q_s : k_s;
#pragma unroll
      for (int m = 0; m < 4; ++m) {
        int row0 = rt * 64 + m * 16 + g * 4;
#pragma unroll
        for (int r = 0; r < 4; ++r)
          dp[((size_t)bh * KSEL + row0 + r) * HDIM + col] = f2bf(acc[m][n][r]);
      }
    }
  }
}

// ---------------- K4: MFMA flash attention; load-balanced qt pairing ----------------
__global__ __launch_bounds__(256) void k_attn_mfma(const short* __restrict__ q_s,
    const short* __restrict__ k_s, const short* __restrict__ v_t,
    short* __restrict__ out_s) {
  __shared__ __align__(16) short Ks[64 * 128];    // [key][dim], chunk^=(key&7)
  __shared__ __align__(16) short Vt[128 * 64];    // [dim][key], chunk^=(dim&7)
  __shared__ __align__(16) short Pl[4 * 16 * 72]; // per-wave P tile, pad 72
  const int i = blockIdx.x;
  const int j = (i >= 256) ? (i - 256) : i;
  const int bh = j & 63;
  const int pr = (j >> 6) & 3;
  const int qt = (i >= 256) ? (7 - pr) : pr;
  const int tid = threadIdx.x;
  const int w = tid >> 6, lane = tid & 63;
  const int g = lane >> 4, r15 = lane & 15;
  const size_t bhbase = (size_t)bh * KSEL * HDIM;
  const int r0 = qt * 64;
  const float scale = 0.08838834764831845f;  // 1/sqrt(128)

  short8 qf[4];
  {
    const short* qrow = q_s + bhbase + (size_t)(r0 + w * 16 + r15) * HDIM;
#pragma unroll
    for (int ks = 0; ks < 4; ++ks)
      qf[ks] = *(const short8*)(qrow + ks * 32 + g * 8);
  }
  f32x4 o[8];
#pragma unroll
  for (int n = 0; n < 8; ++n) o[n] = (f32x4){0.f, 0.f, 0.f, 0.f};
  float mrow[4] = {-INFINITY, -INFINITY, -INFINITY, -INFINITY};
  float lrow[4] = {0.f, 0.f, 0.f, 0.f};

  short* myP = &Pl[w * 16 * 72];
  const int kl16 = lane >> 4, ks16 = lane & 15;
  const int vl8 = lane >> 3, vs8 = lane & 7;

  for (int kt = 0; kt <= qt; ++kt) {
    int l0 = kt * 64;
    __syncthreads();
    {
#pragma unroll
      for (int t = 0; t < 4; ++t) {
        int gi = w * 4 + t;
        int kr0 = gi * 4;
        int key = kr0 + kl16;
        const short* ksrc = k_s + bhbase + (size_t)(l0 + key) * HDIM + ((ks16 ^ (key & 7)) << 3);
        gload16(ksrc, &Ks[kr0 * 128]);
        int d0 = gi * 8;
        int d = d0 + vl8;
        const short* vsrc = v_t + ((size_t)bh * HDIM + d) * KSEL + l0 + ((vs8 ^ (d & 7)) << 3);
        gload16(vsrc, &Vt[d0 * 64]);
      }
    }
    __syncthreads();

    f32x4 s[4];
#pragma unroll
    for (int n = 0; n < 4; ++n) s[n] = (f32x4){0.f, 0.f, 0.f, 0.f};
#pragma unroll
    for (int ks = 0; ks < 4; ++ks) {
#pragma unroll
      for (int n = 0; n < 4; ++n) {
        int row = n * 16 + r15;
        short8 kf = *(const short8*)&Ks[row * 128 + ((ks * 4 + g) ^ (r15 & 7)) * 8];
        s[n] = __builtin_amdgcn_mfma_f32_16x16x32_bf16(qf[ks], kf, s[n], 0, 0, 0);
      }
    }

    const bool diag = (kt == qt);
    float sv[4][4];
#pragma unroll
    for (int n = 0; n < 4; ++n) {
      int key = kt * 64 + n * 16 + r15;
#pragma unroll
      for (int r = 0; r < 4; ++r) {
        float xv = s[n][r] * scale;
        int qrow = r0 + w * 16 + g * 4 + r;
        sv[n][r] = (diag && key > qrow) ? -INFINITY : xv;
      }
    }
    float corr[4];
#pragma unroll
    for (int r = 0; r < 4; ++r) {
      float tm = fmaxf(fmaxf(sv[0][r], sv[1][r]), fmaxf(sv[2][r], sv[3][r]));
#pragma unroll
      for (int off = 8; off; off >>= 1) tm = fmaxf(tm, __shfl_xor(tm, off));
      float newm = fmaxf(mrow[r], tm);
      corr[r] = __expf(mrow[r] - newm);
      mrow[r] = newm;
      float ps = 0.f;
#pragma unroll
      for (int n = 0; n < 4; ++n) {
        float pv = __expf(sv[n][r] - newm);
        sv[n][r] = pv;
        ps += pv;
      }
#pragma unroll
      for (int off = 8; off; off >>= 1) ps += __shfl_xor(ps, off);
      lrow[r] = lrow[r] * corr[r] + ps;
    }
    f32x4 corrv = {corr[0], corr[1], corr[2], corr[3]};
#pragma unroll
    for (int n = 0; n < 4; ++n)
#pragma unroll
      for (int r = 0; r < 4; ++r)
        myP[(g * 4 + r) * 72 + n * 16 + r15] = f2bf(sv[n][r]);
#pragma unroll
    for (int n = 0; n < 8; ++n) o[n] *= corrv;

    short8 pf[2];
#pragma unroll
    for (int ks = 0; ks < 2; ++ks)
      pf[ks] = *(const short8*)&myP[r15 * 72 + ks * 32 + g * 8];
#pragma unroll
    for (int ks = 0; ks < 2; ++ks)
#pragma unroll
      for (int n2 = 0; n2 < 8; ++n2) {
        int row = n2 * 16 + r15;
        short8 vf = *(const short8*)&Vt[row * 64 + ((ks * 4 + g) ^ (r15 & 7)) * 8];
        o[n2] = __builtin_amdgcn_mfma_f32_16x16x32_bf16(pf[ks], vf, o[n2], 0, 0, 0);
      }
  }

  float inv[4];
#pragma unroll
  for (int r = 0; r < 4; ++r) inv[r] = 1.f / lrow[r];
#pragma unroll
  for (int n2 = 0; n2 < 8; ++n2) {
#pragma unroll
    for (int r = 0; r < 4; ++r) {
      int qrow = r0 + w * 16 + g * 4 + r;
      out_s[bhbase + (size_t)qrow * HDIM + n2 * 16 + r15] = f2bf(o[n2][r] * inv[r]);
    }
  }
}

// ---------------- K5b phase 1: P[h,k,c] = out_s_h @ wo_h^T; both operands async-staged ----------------
__global__ __launch_bounds__(256) void k_oproj_p1(
    const short* __restrict__ out_s_b, const short* __restrict__ wob,
    short* __restrict__ P) {
  __shared__ __align__(16) short As[128 * 64];
  __shared__ __align__(16) short Bs[128 * 64];
  const int h = blockIdx.x, rt = blockIdx.y, ct = blockIdx.z;
  const int tid = threadIdx.x;
  const int lane = tid & 63, wid = tid >> 6;
  const int wr = wid >> 1, wc = wid & 1;
  const int l8 = lane >> 3, s8 = lane & 7;
  f32x4 acc[4][4];
#pragma unroll
  for (int m = 0; m < 4; ++m)
#pragma unroll
    for (int n = 0; n < 4; ++n) acc[m][n] = (f32x4){0.f, 0.f, 0.f, 0.f};
  const int r15 = lane & 15, g = lane >> 4;
#pragma unroll
  for (int k0 = 0; k0 < HDIM; k0 += 64) {
    __syncthreads();
    {
#pragma unroll
      for (int t = 0; t < 4; ++t) {
        int gi = wid * 4 + t;
        int r0 = gi * 8;
        int row = r0 + l8;
        const short* asrc = out_s_b + ((size_t)h * KSEL + rt * 128 + row) * HDIM + k0
                          + ((s8 ^ (row & 7)) << 3);
        gload16(asrc, &As[r0 * 64]);
        const short* bsrc = wob + ((size_t)(ct * 128 + row)) * DD + h * HDIM + k0
                          + ((s8 ^ (row & 7)) << 3);
        gload16(bsrc, &Bs[r0 * 64]);
      }
    }
    __syncthreads();
#pragma unroll
    for (int ks = 0; ks < 2; ++ks) {
      short8 af[4], bfr[4];
#pragma unroll
      for (int m = 0; m < 4; ++m) {
        int row = wr * 64 + m * 16 + r15;
        int chunk = (ks * 4 + g) ^ (row & 7);
        af[m] = *(const short8*)&As[row * 64 + chunk * 8];
      }
#pragma unroll
      for (int n = 0; n < 4; ++n) {
        int col = wc * 64 + n * 16 + r15;
        int chunk = (ks * 4 + g) ^ (col & 7);
        bfr[n] = *(const short8*)&Bs[col * 64 + chunk * 8];
      }
#pragma unroll
      for (int m = 0; m < 4; ++m)
#pragma unroll
        for (int n = 0; n < 4; ++n)
          acc[m][n] = __builtin_amdgcn_mfma_f32_16x16x32_bf16(af[m], bfr[n], acc[m][n], 0, 0, 0);
    }
  }
#pragma unroll
  for (int m = 0; m < 4; ++m) {
#pragma unroll
    for (int r = 0; r < 4; ++r) {
      int row = rt * 128 + wr * 64 + m * 16 + g * 4 + r;
#pragma unroll
      for (int n = 0; n < 4; ++n) {
        int col = ct * 128 + wc * 64 + n * 16 + r15;
        P[((size_t)h * KSEL + row) * DD + col] = f2bf(acc[m][n][r]);
      }
    }
  }
}

// ---------------- K5c phase 2: 4 tokens/block (1 wave per token), inv in LDS ----------------
__global__ __launch_bounds__(256) void k_oproj_p2(const short* __restrict__ P,
    const int* __restrict__ inv_b, float* __restrict__ out_b) {
  __shared__ int kidx[4][HH];
  const int t4 = blockIdx.x * 4, tid = threadIdx.x;
  if (tid < 64) kidx[tid >> 4][tid & 15] = inv_b[(tid & 15) * TT + t4 + (tid >> 4)];
  __syncthreads();
  const int tt = tid >> 6, lane = tid & 63;   // one wave per token
  const int t = t4 + tt;
  const int c0 = lane * 32;
  float acc[32];
#pragma unroll
  for (int e = 0; e < 32; ++e) acc[e] = 0.f;
#pragma unroll
  for (int h = 0; h < HH; ++h) {
    int k = kidx[tt][h];
    if (k >= 0) {
      const short* pr = &P[((size_t)h * KSEL + k) * DD + c0];
#pragma unroll
      for (int j = 0; j < 4; ++j) {
        short8 pv = *(const short8*)(pr + j * 8);
#pragma unroll
        for (int e = 0; e < 8; ++e) acc[j * 8 + e] += bf2f(pv[e]);
      }
    }
  }
  float* orow = out_b + (size_t)t * DD + c0;
#pragma unroll
  for (int j = 0; j < 8; ++j) {
    float4 o4 = {acc[j * 4], acc[j * 4 + 1], acc[j * 4 + 2], acc[j * 4 + 3]};
    *(float4*)(orow + j * 4) = o4;
  }
}

extern "C" void kernel_launch(void* const* d_in, const int* in_sizes, int n_in,
                              void* d_out, int out_size, void* d_ws, size_t ws_size,
                              hipStream_t stream) {
  (void)in_sizes; (void)n_in; (void)out_size;
  const float* x  = (const float*)d_in[0];
  const float* wq = (const float*)d_in[1];
  const float* wk = (const float*)d_in[2];
  const float* wv = (const float*)d_in[3];
  const float* wo = (const float*)d_in[4];
  const float* wr = (const float*)d_in[5];
  float* out = (float*)d_out;

  char* ws = (char*)d_ws;
  float* scores = (float*)ws;                                  // 1 MB (unused, layout keep)
  int*   idx    = (int*)(ws + 1048576);                        // 128 KB
  short* wqb    = (short*)(ws + 1179648);                      // 4x 8 MB bf16 weights
  short* wkb    = wqb + 4194304;
  short* wvb    = wkb + 4194304;
  short* wob    = wvb + 4194304;
  short* out_s  = wob + 4194304;                               // 8 MB
  int*   inv    = (int*)((char*)out_s + 8388608);              // 1 MB
  short* P      = (short*)((char*)inv + 1048576);              // 32 MB (per-b reuse)
  short* q_s    = P;
  short* k_s    = P + 4194304;
  short* v_t    = P + 8388608;
  float* part   = (float*)P;                                   // 8 MB (router partials)
  (void)scores;
  const size_t NEED_XB = 144834560ULL;                         // base 77.7MB + xb 64MB
  const int big = (ws_size >= NEED_XB) ? 1 : 0;
  short* xb = big ? (short*)(ws + 77725696) : (short*)ws;      // dummy if !big (unused)

  k_router2<<<dim3(128, 8), 256, 0, stream>>>(x, wr, part, xb, big);
  k_topk<<<NBH + 4096, 512, 0, stream>>>(part, idx, inv, wq, wk, wv, wo, wqb);
  if (big)
    k_qkv_mfma<1><<<512, 256, 0, stream>>>(x, xb, wqb, wkb, wvb, idx, q_s, k_s, v_t);
  else
    k_qkv_mfma<0><<<512, 256, 0, stream>>>(x, xb, wqb, wkb, wvb, idx, q_s, k_s, v_t);
  k_attn_mfma<<<512, 256, 0, stream>>>(q_s, k_s, v_t, out_s);
  for (int b = 0; b < BB; ++b) {
    k_oproj_p1<<<dim3(HH, KSEL / 128, DD / 128), 256, 0, stream>>>(
        out_s + (size_t)b * HH * KSEL * HDIM, wob, P);
    k_oproj_p2<<<TT / 4, 256, 0, stream>>>(
        P, inv + (size_t)b * HH * TT, out + (size_t)b * TT * DD);
  }
}

// Round 20
// 270.565 us; speedup vs baseline: 1.0699x; 1.0699x over previous
//
#include <hip/hip_runtime.h>
#include <math.h>

#define BB 4
#define TT 4096
#define DD 2048
#define HH 16
#define HDIM 128
#define KSEL 512
#define NBH (BB*HH)

using short8  = __attribute__((ext_vector_type(8))) short;
using short4v = __attribute__((ext_vector_type(4))) short;
using f32x4   = __attribute__((ext_vector_type(4))) float;

__device__ __forceinline__ short f2bf(float f) {
  unsigned u = __float_as_uint(f);
  u += 0x7fffu + ((u >> 16) & 1u);   // round-nearest-even
  return (short)(u >> 16);
}
__device__ __forceinline__ float bf2f(short s) {
  return __uint_as_float(((unsigned)(unsigned short)s) << 16);
}

// async global->LDS, 16B per lane; LDS dest wave-uniform base + lane*16
__device__ __forceinline__ void gload16(const short* g, short* l) {
  __builtin_amdgcn_global_load_lds(
      (const __attribute__((address_space(1))) void*)g,
      (__attribute__((address_space(3))) void*)l, 16, 0, 0);
}

// ---------------- K0: one-time f32->bf16 weight conversion ----------------
__global__ __launch_bounds__(256) void k_cvt_w(const float* __restrict__ wq,
    const float* __restrict__ wk, const float* __restrict__ wv,
    const float* __restrict__ wo, short* __restrict__ dst) {
  const int wsel = blockIdx.y;
  const float* s = (wsel == 0) ? wq : (wsel == 1) ? wk : (wsel == 2) ? wv : wo;
  size_t base = (size_t)blockIdx.x * 2048 + (size_t)threadIdx.x * 8;
  float4 a = *(const float4*)(s + base);
  float4 b = *(const float4*)(s + base + 4);
  short8 o;
  o[0] = f2bf(a.x); o[1] = f2bf(a.y); o[2] = f2bf(a.z); o[3] = f2bf(a.w);
  o[4] = f2bf(b.x); o[5] = f2bf(b.y); o[6] = f2bf(b.z); o[7] = f2bf(b.w);
  *(short8*)&dst[(size_t)wsel * 4194304 + base] = o;
}

// ---------------- K1: router scores, split-K f32 GEMM; fused bf16-x side-write ----------------
__global__ __launch_bounds__(256) void k_router2(const float* __restrict__ x,
    const float* __restrict__ wr, float* __restrict__ part,
    short* __restrict__ xb, const int writeXb) {
  __shared__ __align__(16) float Xs[128][36];
  __shared__ __align__(16) float Ws[16][36];
  const int tb = blockIdx.x, kq = blockIdx.y;
  const int tid = threadIdx.x;
  const int row0 = tb * 128;
  const int sr8 = tid >> 3, sc8 = (tid & 7) * 4;   // stage map: 8 thr/row, 128B runs
  const int tq = tid >> 2, hq = tid & 3;           // compute map
  const int kbase = kq * 256;
  float acc[2][4];
#pragma unroll
  for (int i = 0; i < 2; ++i)
#pragma unroll
    for (int j = 0; j < 4; ++j) acc[i][j] = 0.f;
  float4 xr[4], wreg;
  {
#pragma unroll
    for (int p = 0; p < 4; ++p)
      xr[p] = *(const float4*)(x + (size_t)(row0 + sr8 + p * 32) * DD + kbase + sc8);
    if (tid < 128) wreg = *(const float4*)(wr + (size_t)(tid >> 3) * DD + kbase + (tid & 7) * 4);
  }
  for (int c = 0; c < 8; ++c) {
    if (c) __syncthreads();
#pragma unroll
    for (int p = 0; p < 4; ++p) {
      *(float4*)&Xs[sr8 + p * 32][sc8] = xr[p];
      if (writeXb) {
        short4v b4;
        b4[0] = f2bf(xr[p].x); b4[1] = f2bf(xr[p].y);
        b4[2] = f2bf(xr[p].z); b4[3] = f2bf(xr[p].w);
        *(short4v*)(xb + (size_t)(row0 + sr8 + p * 32) * DD + kbase + c * 32 + sc8) = b4;
      }
    }
    if (tid < 128) *(float4*)&Ws[tid >> 3][(tid & 7) * 4] = wreg;
    __syncthreads();
    if (c < 7) {
      const int k0 = kbase + (c + 1) * 32;
#pragma unroll
      for (int p = 0; p < 4; ++p)
        xr[p] = *(const float4*)(x + (size_t)(row0 + sr8 + p * 32) * DD + k0 + sc8);
      if (tid < 128) wreg = *(const float4*)(wr + (size_t)(tid >> 3) * DD + k0 + (tid & 7) * 4);
    }
#pragma unroll
    for (int k4 = 0; k4 < 8; ++k4) {
      float4 xv0 = *(const float4*)&Xs[tq][k4 * 4];
      float4 xv1 = *(const float4*)&Xs[tq + 64][k4 * 4];
#pragma unroll
      for (int j = 0; j < 4; ++j) {
        float4 wv4 = *(const float4*)&Ws[hq + j * 4][k4 * 4];
        acc[0][j] += xv0.x * wv4.x + xv0.y * wv4.y + xv0.z * wv4.z + xv0.w * wv4.w;
        acc[1][j] += xv1.x * wv4.x + xv1.y * wv4.y + xv1.z * wv4.z + xv1.w * wv4.w;
      }
    }
  }
#pragma unroll
  for (int i = 0; i < 2; ++i) {
    int tg = row0 + tq + i * 64;
    int b = tg >> 12, t = tg & (TT - 1);
#pragma unroll
    for (int j = 0; j < 4; ++j)
      part[((size_t)kq * NBH + (b * HH + hq + j * 4)) * TT + t] = acc[i][j];
  }
}

// ---------------- K2: per-(b,h) top-512 via exact radix-select; fused split-K sum + inverse map ----------------
__global__ __launch_bounds__(512) void k_topk(const float* __restrict__ part,
                                              int* __restrict__ idx,
                                              int* __restrict__ inv) {
  __shared__ unsigned hist[256];
  __shared__ unsigned ssum[257];
  __shared__ unsigned wtot[8];
  __shared__ unsigned sh_b;
  const int bh = blockIdx.x, tid = threadIdx.x;
  const int lane = tid & 63, wv = tid >> 6;
  const size_t S = (size_t)NBH * TT;
  const float* pb = part + (size_t)bh * TT + tid * 8;
  unsigned key[8];
  {
    float4 s0 = *(const float4*)(pb);
    float4 s1 = *(const float4*)(pb + 4);
#pragma unroll
    for (int k = 1; k < 8; ++k) {
      float4 v0 = *(const float4*)(pb + k * S);
      float4 v1 = *(const float4*)(pb + k * S + 4);
      s0.x += v0.x; s0.y += v0.y; s0.z += v0.z; s0.w += v0.w;
      s1.x += v1.x; s1.y += v1.y; s1.z += v1.z; s1.w += v1.w;
    }
    float vs[8] = {s0.x, s0.y, s0.z, s0.w, s1.x, s1.y, s1.z, s1.w};
#pragma unroll
    for (int i = 0; i < 8; ++i) {
      unsigned u = __float_as_uint(vs[i]);
      key[i] = (u & 0x80000000u) ? ~u : (u | 0x80000000u);  // monotone map
    }
  }
  unsigned prefix = 0, need = KSEL;
  for (int shift = 24; shift >= 0; shift -= 8) {
    if (tid < 256) hist[tid] = 0;
    __syncthreads();
#pragma unroll
    for (int i = 0; i < 8; ++i) {
      bool m = (shift == 24) || ((key[i] >> (shift + 8)) == prefix);
      if (m) atomicAdd(&hist[(key[i] >> shift) & 255], 1u);
    }
    __syncthreads();
    if (wv == 0) {
      unsigned v0 = hist[lane * 4], v1 = hist[lane * 4 + 1];
      unsigned v2 = hist[lane * 4 + 2], v3 = hist[lane * 4 + 3];
      unsigned s3 = v3, s2 = v2 + s3, s1 = v1 + s2, s0 = v0 + s1;
      unsigned t = s0;
#pragma unroll
      for (int off = 1; off < 64; off <<= 1) {
        unsigned o = __shfl_down(t, off);
        if (lane + off < 64) t += o;
      }
      unsigned above = t - s0;
      ssum[lane * 4]     = s0 + above;
      ssum[lane * 4 + 1] = s1 + above;
      ssum[lane * 4 + 2] = s2 + above;
      ssum[lane * 4 + 3] = s3 + above;
      if (lane == 0) ssum[256] = 0;
    }
    __syncthreads();
    if (tid < 256) {
      if (ssum[tid] >= need && ssum[tid + 1] < need) sh_b = (unsigned)tid;
    }
    __syncthreads();
    unsigned bstar = sh_b;
    need -= ssum[bstar + 1];
    prefix = (shift == 24) ? bstar : ((prefix << 8) | bstar);
  }
  const unsigned thr = prefix;
  unsigned cgt = 0, ceq = 0;
#pragma unroll
  for (int i = 0; i < 8; ++i) { cgt += (key[i] > thr); ceq += (key[i] == thr); }
  unsigned packed = (cgt << 16) | ceq;
  unsigned inc = packed;
#pragma unroll
  for (int off = 1; off < 64; off <<= 1) {
    unsigned o = __shfl_up(inc, off);
    if (lane >= off) inc += o;
  }
  if (lane == 63) wtot[wv] = inc;
  __syncthreads();
  unsigned wbase = 0;
#pragma unroll
  for (int w2 = 0; w2 < 8; ++w2) wbase += (w2 < wv) ? wtot[w2] : 0u;
  unsigned base = wbase + inc - packed;
  unsigned gt_before = base >> 16, eq_before = base & 0xffffu;
  int* op = idx + bh * KSEL;
  int* invrow = inv + (size_t)bh * TT;
#pragma unroll
  for (int i = 0; i < 8; ++i) {
    bool isgt = key[i] > thr, iseq = key[i] == thr;
    bool sel = isgt || (iseq && eq_before < need);
    int pos = -1;
    if (sel) {
      pos = (int)(gt_before + (eq_before < need ? eq_before : need));
      op[pos] = tid * 8 + i;
    }
    invrow[tid * 8 + i] = pos;
    gt_before += isgt; eq_before += iseq;
  }
}

// ---------------- K3: merged gathered QKV projection via bf16 MFMA (round-10/15 proven) ----------------
template <int AB>
__global__ __launch_bounds__(256, 2) void k_qkv_mfma(
    const float* __restrict__ x, const short* __restrict__ xb,
    const short* __restrict__ wqb, const short* __restrict__ wkb,
    const short* __restrict__ wvb, const int* __restrict__ idx,
    short* __restrict__ q_s, short* __restrict__ k_s, short* __restrict__ v_t) {
  __shared__ __align__(16) short As[64 * 64];
  __shared__ __align__(16) short Bs[3][128 * 64];
  __shared__ int tIdx[64];
  const int L = blockIdx.x;            // [bhhi:3][rt:3][xcd:3]
  const int xcd = L & 7;
  const int bh = xcd * 8 + (L >> 6);
  const int rt = (L >> 3) & 7;
  const int b = bh >> 4, h = bh & 15;
  const int tid = threadIdx.x;
  if (tid < 64) tIdx[tid] = idx[bh * KSEL + rt * 64 + tid];
  __syncthreads();
  const int lane = tid & 63, w = tid >> 6;
  const int g = lane >> 4, r15 = lane & 15;
  const int lcol8 = lane >> 3, lslot = lane & 7; // stage lane mapping
  const float* aPtr = nullptr;
  const short* aSrc0 = nullptr; const short* aSrc1 = nullptr;
  int arow = 0, rm = 0;
  if constexpr (AB) {
    int rowA0 = w * 16 + lcol8;
    int rowA1 = rowA0 + 8;
    aSrc0 = xb + ((size_t)b * TT + tIdx[rowA0]) * DD + ((lslot ^ lcol8) << 3);
    aSrc1 = xb + ((size_t)b * TT + tIdx[rowA1]) * DD + ((lslot ^ lcol8) << 3);
  } else {
    arow = tid >> 2;
    rm = arow & 7;
    aPtr = x + ((size_t)b * TT + tIdx[arow]) * DD + (tid & 3) * 16;
  }
  f32x4 acc[4][6];
#pragma unroll
  for (int m = 0; m < 4; ++m)
#pragma unroll
    for (int n = 0; n < 6; ++n) acc[m][n] = (f32x4){0.f, 0.f, 0.f, 0.f};
  for (int k0 = 0; k0 < DD; k0 += 64) {
    __syncthreads();
    {
      if constexpr (AB) {
        gload16(aSrc0 + k0, &As[(w * 16) * 64]);
        gload16(aSrc1 + k0, &As[(w * 16 + 8) * 64]);
      } else {
        float4 a0 = *(const float4*)(aPtr + k0);
        float4 a1 = *(const float4*)(aPtr + k0 + 4);
        float4 a2 = *(const float4*)(aPtr + k0 + 8);
        float4 a3 = *(const float4*)(aPtr + k0 + 12);
        short8 p0, p1;
        p0[0] = f2bf(a0.x); p0[1] = f2bf(a0.y); p0[2] = f2bf(a0.z); p0[3] = f2bf(a0.w);
        p0[4] = f2bf(a1.x); p0[5] = f2bf(a1.y); p0[6] = f2bf(a1.z); p0[7] = f2bf(a1.w);
        p1[0] = f2bf(a2.x); p1[1] = f2bf(a2.y); p1[2] = f2bf(a2.z); p1[3] = f2bf(a2.w);
        p1[4] = f2bf(a3.x); p1[5] = f2bf(a3.y); p1[6] = f2bf(a3.z); p1[7] = f2bf(a3.w);
        int kq = tid & 3;
        *(short8*)&As[arow * 64 + ((2 * kq) ^ rm) * 8] = p0;
        *(short8*)&As[arow * 64 + ((2 * kq + 1) ^ rm) * 8] = p1;
      }
#pragma unroll
      for (int t = 0; t < 12; ++t) {
        int gi = w * 12 + t;
        int p = gi >> 4;
        int c0 = (gi & 15) << 3;
        int col = c0 + lcol8;
        const short* wsrc = (p == 0 ? wqb : p == 1 ? wkb : wvb)
                          + ((size_t)(h * HDIM + col)) * DD + k0 + ((lslot ^ (col & 7)) << 3);
        gload16(wsrc, &Bs[p][c0 * 64]);
      }
    }
    __syncthreads();
#pragma unroll
    for (int ks = 0; ks < 2; ++ks) {
      short8 af[4], bfr[6];
#pragma unroll
      for (int m = 0; m < 4; ++m) {
        int row = m * 16 + r15;
        af[m] = *(const short8*)&As[row * 64 + ((ks * 4 + g) ^ (row & 7)) * 8];
      }
#pragma unroll
      for (int n = 0; n < 6; ++n) {
        int nf = w * 6 + n;
        int colr = (nf & 7) * 16 + r15;
        bfr[n] = *(const short8*)&Bs[nf >> 3][colr * 64 + ((ks * 4 + g) ^ (colr & 7)) * 8];
      }
#pragma unroll
      for (int m = 0; m < 4; ++m)
#pragma unroll
        for (int n = 0; n < 6; ++n)
          acc[m][n] = __builtin_amdgcn_mfma_f32_16x16x32_bf16(af[m], bfr[n], acc[m][n], 0, 0, 0);
    }
  }
#pragma unroll
  for (int n = 0; n < 6; ++n) {
    int nf = w * 6 + n;
    int p = nf >> 3;
    int col = (nf & 7) * 16 + r15;
    if (p == 2) {
#pragma unroll
      for (int m = 0; m < 4; ++m) {
        short4v pk;
#pragma unroll
        for (int r = 0; r < 4; ++r) pk[r] = f2bf(acc[m][n][r]);
        *(short4v*)&v_t[((size_t)bh * HDIM + col) * KSEL + rt * 64 + m * 16 + g * 4] = pk;
      }
    } else {
      short* dp = (p == 0) ? q_s : k_s;
#pragma unroll
      for (int m = 0; m < 4; ++m) {
        int row0 = rt * 64 + m * 16 + g * 4;
#pragma unroll
        for (int r = 0; r < 4; ++r)
          dp[((size_t)bh * KSEL + row0 + r) * HDIM + col] = f2bf(acc[m][n][r]);
      }
    }
  }
}

// ---------------- K4: MFMA flash attention; load-balanced qt pairing ----------------
__global__ __launch_bounds__(256) void k_attn_mfma(const short* __restrict__ q_s,
    const short* __restrict__ k_s, const short* __restrict__ v_t,
    short* __restrict__ out_s) {
  __shared__ __align__(16) short Ks[64 * 128];    // [key][dim], chunk^=(key&7)
  __shared__ __align__(16) short Vt[128 * 64];    // [dim][key], chunk^=(dim&7)
  __shared__ __align__(16) short Pl[4 * 16 * 72]; // per-wave P tile, pad 72
  const int i = blockIdx.x;
  const int j = (i >= 256) ? (i - 256) : i;
  const int bh = j & 63;
  const int pr = (j >> 6) & 3;
  const int qt = (i >= 256) ? (7 - pr) : pr;
  const int tid = threadIdx.x;
  const int w = tid >> 6, lane = tid & 63;
  const int g = lane >> 4, r15 = lane & 15;
  const size_t bhbase = (size_t)bh * KSEL * HDIM;
  const int r0 = qt * 64;
  const float scale = 0.08838834764831845f;  // 1/sqrt(128)

  short8 qf[4];
  {
    const short* qrow = q_s + bhbase + (size_t)(r0 + w * 16 + r15) * HDIM;
#pragma unroll
    for (int ks = 0; ks < 4; ++ks)
      qf[ks] = *(const short8*)(qrow + ks * 32 + g * 8);
  }
  f32x4 o[8];
#pragma unroll
  for (int n = 0; n < 8; ++n) o[n] = (f32x4){0.f, 0.f, 0.f, 0.f};
  float mrow[4] = {-INFINITY, -INFINITY, -INFINITY, -INFINITY};
  float lrow[4] = {0.f, 0.f, 0.f, 0.f};

  short* myP = &Pl[w * 16 * 72];
  const int kl16 = lane >> 4, ks16 = lane & 15;
  const int vl8 = lane >> 3, vs8 = lane & 7;

  for (int kt = 0; kt <= qt; ++kt) {
    int l0 = kt * 64;
    __syncthreads();
    {
#pragma unroll
      for (int t = 0; t < 4; ++t) {
        int gi = w * 4 + t;
        int kr0 = gi * 4;
        int key = kr0 + kl16;
        const short* ksrc = k_s + bhbase + (size_t)(l0 + key) * HDIM + ((ks16 ^ (key & 7)) << 3);
        gload16(ksrc, &Ks[kr0 * 128]);
        int d0 = gi * 8;
        int d = d0 + vl8;
        const short* vsrc = v_t + ((size_t)bh * HDIM + d) * KSEL + l0 + ((vs8 ^ (d & 7)) << 3);
        gload16(vsrc, &Vt[d0 * 64]);
      }
    }
    __syncthreads();

    f32x4 s[4];
#pragma unroll
    for (int n = 0; n < 4; ++n) s[n] = (f32x4){0.f, 0.f, 0.f, 0.f};
#pragma unroll
    for (int ks = 0; ks < 4; ++ks) {
#pragma unroll
      for (int n = 0; n < 4; ++n) {
        int row = n * 16 + r15;
        short8 kf = *(const short8*)&Ks[row * 128 + ((ks * 4 + g) ^ (r15 & 7)) * 8];
        s[n] = __builtin_amdgcn_mfma_f32_16x16x32_bf16(qf[ks], kf, s[n], 0, 0, 0);
      }
    }

    const bool diag = (kt == qt);
    float sv[4][4];
#pragma unroll
    for (int n = 0; n < 4; ++n) {
      int key = kt * 64 + n * 16 + r15;
#pragma unroll
      for (int r = 0; r < 4; ++r) {
        float xv = s[n][r] * scale;
        int qrow = r0 + w * 16 + g * 4 + r;
        sv[n][r] = (diag && key > qrow) ? -INFINITY : xv;
      }
    }
    float corr[4];
#pragma unroll
    for (int r = 0; r < 4; ++r) {
      float tm = fmaxf(fmaxf(sv[0][r], sv[1][r]), fmaxf(sv[2][r], sv[3][r]));
#pragma unroll
      for (int off = 8; off; off >>= 1) tm = fmaxf(tm, __shfl_xor(tm, off));
      float newm = fmaxf(mrow[r], tm);
      corr[r] = __expf(mrow[r] - newm);
      mrow[r] = newm;
      float ps = 0.f;
#pragma unroll
      for (int n = 0; n < 4; ++n) {
        float pv = __expf(sv[n][r] - newm);
        sv[n][r] = pv;
        ps += pv;
      }
#pragma unroll
      for (int off = 8; off; off >>= 1) ps += __shfl_xor(ps, off);
      lrow[r] = lrow[r] * corr[r] + ps;
    }
    f32x4 corrv = {corr[0], corr[1], corr[2], corr[3]};
#pragma unroll
    for (int n = 0; n < 4; ++n)
#pragma unroll
      for (int r = 0; r < 4; ++r)
        myP[(g * 4 + r) * 72 + n * 16 + r15] = f2bf(sv[n][r]);
#pragma unroll
    for (int n = 0; n < 8; ++n) o[n] *= corrv;

    short8 pf[2];
#pragma unroll
    for (int ks = 0; ks < 2; ++ks)
      pf[ks] = *(const short8*)&myP[r15 * 72 + ks * 32 + g * 8];
#pragma unroll
    for (int ks = 0; ks < 2; ++ks)
#pragma unroll
      for (int n2 = 0; n2 < 8; ++n2) {
        int row = n2 * 16 + r15;
        short8 vf = *(const short8*)&Vt[row * 64 + ((ks * 4 + g) ^ (r15 & 7)) * 8];
        o[n2] = __builtin_amdgcn_mfma_f32_16x16x32_bf16(pf[ks], vf, o[n2], 0, 0, 0);
      }
  }

  float inv[4];
#pragma unroll
  for (int r = 0; r < 4; ++r) inv[r] = 1.f / lrow[r];
#pragma unroll
  for (int n2 = 0; n2 < 8; ++n2) {
#pragma unroll
    for (int r = 0; r < 4; ++r) {
      int qrow = r0 + w * 16 + g * 4 + r;
      out_s[bhbase + (size_t)qrow * HDIM + n2 * 16 + r15] = f2bf(o[n2][r] * inv[r]);
    }
  }
}

// ---------------- K5b phase 1: P[h,k,c] = out_s_h @ wo_h^T; both operands async-staged ----------------
__global__ __launch_bounds__(256) void k_oproj_p1(
    const short* __restrict__ out_s_b, const short* __restrict__ wob,
    short* __restrict__ P) {
  __shared__ __align__(16) short As[128 * 64];
  __shared__ __align__(16) short Bs[128 * 64];
  const int h = blockIdx.x, rt = blockIdx.y, ct = blockIdx.z;
  const int tid = threadIdx.x;
  const int lane = tid & 63, wid = tid >> 6;
  const int wr = wid >> 1, wc = wid & 1;
  const int l8 = lane >> 3, s8 = lane & 7;
  f32x4 acc[4][4];
#pragma unroll
  for (int m = 0; m < 4; ++m)
#pragma unroll
    for (int n = 0; n < 4; ++n) acc[m][n] = (f32x4){0.f, 0.f, 0.f, 0.f};
  const int r15 = lane & 15, g = lane >> 4;
#pragma unroll
  for (int k0 = 0; k0 < HDIM; k0 += 64) {
    __syncthreads();
    {
#pragma unroll
      for (int t = 0; t < 4; ++t) {
        int gi = wid * 4 + t;
        int r0 = gi * 8;
        int row = r0 + l8;
        const short* asrc = out_s_b + ((size_t)h * KSEL + rt * 128 + row) * HDIM + k0
                          + ((s8 ^ (row & 7)) << 3);
        gload16(asrc, &As[r0 * 64]);
        const short* bsrc = wob + ((size_t)(ct * 128 + row)) * DD + h * HDIM + k0
                          + ((s8 ^ (row & 7)) << 3);
        gload16(bsrc, &Bs[r0 * 64]);
      }
    }
    __syncthreads();
#pragma unroll
    for (int ks = 0; ks < 2; ++ks) {
      short8 af[4], bfr[4];
#pragma unroll
      for (int m = 0; m < 4; ++m) {
        int row = wr * 64 + m * 16 + r15;
        int chunk = (ks * 4 + g) ^ (row & 7);
        af[m] = *(const short8*)&As[row * 64 + chunk * 8];
      }
#pragma unroll
      for (int n = 0; n < 4; ++n) {
        int col = wc * 64 + n * 16 + r15;
        int chunk = (ks * 4 + g) ^ (col & 7);
        bfr[n] = *(const short8*)&Bs[col * 64 + chunk * 8];
      }
#pragma unroll
      for (int m = 0; m < 4; ++m)
#pragma unroll
        for (int n = 0; n < 4; ++n)
          acc[m][n] = __builtin_amdgcn_mfma_f32_16x16x32_bf16(af[m], bfr[n], acc[m][n], 0, 0, 0);
    }
  }
#pragma unroll
  for (int m = 0; m < 4; ++m) {
#pragma unroll
    for (int r = 0; r < 4; ++r) {
      int row = rt * 128 + wr * 64 + m * 16 + g * 4 + r;
#pragma unroll
      for (int n = 0; n < 4; ++n) {
        int col = ct * 128 + wc * 64 + n * 16 + r15;
        P[((size_t)h * KSEL + row) * DD + col] = f2bf(acc[m][n][r]);
      }
    }
  }
}

// ---------------- K5c phase 2: per-token gather-reduce; inv preloaded to LDS ----------------
__global__ __launch_bounds__(256) void k_oproj_p2(const short* __restrict__ P,
    const int* __restrict__ inv_b, float* __restrict__ out_b) {
  __shared__ int kidx[HH];
  const int t = blockIdx.x, tid = threadIdx.x;
  if (tid < HH) kidx[tid] = inv_b[tid * TT + t];
  __syncthreads();
  const int c0 = tid * 8;
  float acc[8] = {0.f, 0.f, 0.f, 0.f, 0.f, 0.f, 0.f, 0.f};
#pragma unroll
  for (int h = 0; h < HH; ++h) {
    int k = kidx[h];
    if (k >= 0) {
      short8 pv = *(const short8*)&P[((size_t)h * KSEL + k) * DD + c0];
#pragma unroll
      for (int e = 0; e < 8; ++e) acc[e] += bf2f(pv[e]);
    }
  }
  float4 o0 = {acc[0], acc[1], acc[2], acc[3]};
  float4 o1 = {acc[4], acc[5], acc[6], acc[7]};
  *(float4*)&out_b[(size_t)t * DD + c0] = o0;
  *(float4*)&out_b[(size_t)t * DD + c0 + 4] = o1;
}

extern "C" void kernel_launch(void* const* d_in, const int* in_sizes, int n_in,
                              void* d_out, int out_size, void* d_ws, size_t ws_size,
                              hipStream_t stream) {
  (void)in_sizes; (void)n_in; (void)out_size;
  const float* x  = (const float*)d_in[0];
  const float* wq = (const float*)d_in[1];
  const float* wk = (const float*)d_in[2];
  const float* wv = (const float*)d_in[3];
  const float* wo = (const float*)d_in[4];
  const float* wr = (const float*)d_in[5];
  float* out = (float*)d_out;

  char* ws = (char*)d_ws;
  float* scores = (float*)ws;                                  // 1 MB (unused, layout keep)
  int*   idx    = (int*)(ws + 1048576);                        // 128 KB
  short* wqb    = (short*)(ws + 1179648);                      // 4x 8 MB bf16 weights
  short* wkb    = wqb + 4194304;
  short* wvb    = wkb + 4194304;
  short* wob    = wvb + 4194304;
  short* out_s  = wob + 4194304;                               // 8 MB
  int*   inv    = (int*)((char*)out_s + 8388608);              // 1 MB
  short* P      = (short*)((char*)inv + 1048576);              // 32 MB (per-b reuse)
  short* q_s    = P;
  short* k_s    = P + 4194304;
  short* v_t    = P + 8388608;
  float* part   = (float*)P;                                   // 8 MB (router partials)
  (void)scores;
  const size_t NEED_XB = 144834560ULL;                         // base 77.7MB + xb 64MB
  const int big = (ws_size >= NEED_XB) ? 1 : 0;
  short* xb = big ? (short*)(ws + 77725696) : (short*)ws;      // dummy if !big (unused)

  k_cvt_w<<<dim3(2048, 4), 256, 0, stream>>>(wq, wk, wv, wo, wqb);
  k_router2<<<dim3(128, 8), 256, 0, stream>>>(x, wr, part, xb, big);
  k_topk<<<NBH, 512, 0, stream>>>(part, idx, inv);
  if (big)
    k_qkv_mfma<1><<<512, 256, 0, stream>>>(x, xb, wqb, wkb, wvb, idx, q_s, k_s, v_t);
  else
    k_qkv_mfma<0><<<512, 256, 0, stream>>>(x, xb, wqb, wkb, wvb, idx, q_s, k_s, v_t);
  k_attn_mfma<<<512, 256, 0, stream>>>(q_s, k_s, v_t, out_s);
  for (int b = 0; b < BB; ++b) {
    k_oproj_p1<<<dim3(HH, KSEL / 128, DD / 128), 256, 0, stream>>>(
        out_s + (size_t)b * HH * KSEL * HDIM, wob, P);
    k_oproj_p2<<<TT, 256, 0, stream>>>(
        P, inv + (size_t)b * HH * TT, out + (size_t)b * TT * DD);
  }
}